// Round 2
// baseline (1089.347 us; speedup 1.0000x reference)
//
#include <hip/hip_runtime.h>
#include <math.h>

#define SEQ 512
#define DMODEL 512
#define NHEAD 8
#define DHEAD 64

// ---------------------------------------------------------------------------
// Kernel 1: q/k/v projections.  q = (query@Wq+bq)/8, k = key@Wk+bk, v = ...
// Plain 16x16 LDS-tiled GEMM, fp32, outputs into workspace laid out
// [l, h*64+d] (the pre-split-heads [L, DMODEL] matrix).
// ---------------------------------------------------------------------------
__global__ __launch_bounds__(256) void proj_kernel(
    const float* __restrict__ query, const float* __restrict__ key_in, const float* __restrict__ value,
    const float* __restrict__ Wq, const float* __restrict__ bq,
    const float* __restrict__ Wk, const float* __restrict__ bk,
    const float* __restrict__ Wv, const float* __restrict__ bv,
    float* __restrict__ ws)
{
    const int which = blockIdx.z;
    const float* A    = which == 0 ? query : (which == 1 ? key_in : value);
    const float* W    = which == 0 ? Wq    : (which == 1 ? Wk     : Wv);
    const float* bias = which == 0 ? bq    : (which == 1 ? bk     : bv);
    const float scale = which == 0 ? 0.125f : 1.0f;   // 1/sqrt(DHEAD)
    float* C = ws + (size_t)which * (SEQ * DMODEL);

    __shared__ float As[16][17];
    __shared__ float Bs[16][17];
    const int tx = threadIdx.x, ty = threadIdx.y;
    const int row = blockIdx.y * 16 + ty;
    const int col = blockIdx.x * 16 + tx;
    float acc = 0.f;
    for (int t = 0; t < DMODEL / 16; ++t) {
        As[ty][tx] = A[(size_t)row * DMODEL + t * 16 + tx];
        Bs[ty][tx] = W[(size_t)(t * 16 + ty) * DMODEL + col];
        __syncthreads();
        #pragma unroll
        for (int kk = 0; kk < 16; ++kk) acc += As[ty][kk] * Bs[kk][tx];
        __syncthreads();
    }
    C[(size_t)row * DMODEL + col] = scale * (acc + bias[col]);
}

// ---------------------------------------------------------------------------
// Kernel 2: logits + softmax.  One workgroup per (h,l).
// logits[m] = sum_d q[h,l,d] * (k[h,m,d] + rk[h,l,m,d])   (fused einsums)
// Lane layout: lane = 16*mi + di ; lane loads rk[m_base+mi, 4*di .. 4*di+3]
// -> each wave reads a contiguous 1 KB chunk per iteration (fully coalesced).
// Softmax in fp32 in LDS; attn written fp32 to d_out (it IS output 1).
// ---------------------------------------------------------------------------
__global__ __launch_bounds__(256) void attn_kernel(
    const float* __restrict__ rk, const float* __restrict__ ws_q,
    const float* __restrict__ ws_k, float* __restrict__ attn_out)
{
    const int l = blockIdx.x, h = blockIdx.y;
    const int tid = threadIdx.x;
    const int wave = tid >> 6, lane = tid & 63;
    const int mi = lane >> 4, di = lane & 15;

    __shared__ float qrow[DHEAD];
    __shared__ float logits[SEQ];
    __shared__ float sred[4];

    if (tid < DHEAD) qrow[tid] = ws_q[(size_t)l * DMODEL + h * DHEAD + tid];
    __syncthreads();

    float qv[4];
    #pragma unroll
    for (int j = 0; j < 4; ++j) qv[j] = qrow[4 * di + j];

    const float* rk_base = rk + ((size_t)h * SEQ + l) * SEQ * DHEAD;

    for (int it = 0; it < 32; ++it) {
        const int m = it * 16 + wave * 4 + mi;
        float4 r = *reinterpret_cast<const float4*>(rk_base + (size_t)m * DHEAD + 4 * di);
        float4 k0 = *reinterpret_cast<const float4*>(ws_k + (size_t)m * DMODEL + h * DHEAD + 4 * di);
        float s = qv[0] * (k0.x + r.x) + qv[1] * (k0.y + r.y)
                + qv[2] * (k0.z + r.z) + qv[3] * (k0.w + r.w);
        s += __shfl_xor(s, 1, 64);
        s += __shfl_xor(s, 2, 64);
        s += __shfl_xor(s, 4, 64);
        s += __shfl_xor(s, 8, 64);
        if (di == 0) logits[m] = s;
    }
    __syncthreads();

    // softmax over 512 logits; each thread owns 2
    const float l0 = logits[tid], l1 = logits[tid + 256];
    float v = fmaxf(l0, l1);
    #pragma unroll
    for (int off = 32; off >= 1; off >>= 1) v = fmaxf(v, __shfl_xor(v, off, 64));
    if (lane == 0) sred[wave] = v;
    __syncthreads();
    const float maxv = fmaxf(fmaxf(sred[0], sred[1]), fmaxf(sred[2], sred[3]));
    __syncthreads();
    const float e0 = expf(l0 - maxv), e1 = expf(l1 - maxv);
    v = e0 + e1;
    #pragma unroll
    for (int off = 32; off >= 1; off >>= 1) v += __shfl_xor(v, off, 64);
    if (lane == 0) sred[wave] = v;
    __syncthreads();
    const float inv = 1.0f / (sred[0] + sred[1] + sred[2] + sred[3]);
    const size_t base = ((size_t)h * SEQ + l) * SEQ;
    attn_out[base + tid]       = e0 * inv;
    attn_out[base + tid + 256] = e1 * inv;
}

// ---------------------------------------------------------------------------
// Kernel 3: context.  One workgroup per (h,l).
// context[d] = sum_m attn[m] * (v[h,m,d] + rv[h,l,m,d])
// Same streaming lane layout as attn_kernel; cross-mi shfl reduce then
// cross-wave LDS reduce.  Output fp32 [l, h*64+d] in workspace.
// ---------------------------------------------------------------------------
__global__ __launch_bounds__(256) void ctx_kernel(
    const float* __restrict__ rv, const float* __restrict__ ws_v,
    const float* __restrict__ attn, float* __restrict__ ws_ctx)
{
    const int l = blockIdx.x, h = blockIdx.y;
    const int tid = threadIdx.x;
    const int wave = tid >> 6, lane = tid & 63;
    const int mi = lane >> 4, di = lane & 15;

    __shared__ float arow[SEQ];
    __shared__ float part[4][DHEAD];

    const size_t abase = ((size_t)h * SEQ + l) * SEQ;
    arow[tid]       = attn[abase + tid];
    arow[tid + 256] = attn[abase + tid + 256];
    __syncthreads();

    float acc[4] = {0.f, 0.f, 0.f, 0.f};
    const float* rv_base = rv + ((size_t)h * SEQ + l) * SEQ * DHEAD;
    for (int it = 0; it < 32; ++it) {
        const int m = it * 16 + wave * 4 + mi;
        const float a = arow[m];
        float4 r = *reinterpret_cast<const float4*>(rv_base + (size_t)m * DHEAD + 4 * di);
        float4 v0 = *reinterpret_cast<const float4*>(ws_v + (size_t)m * DMODEL + h * DHEAD + 4 * di);
        acc[0] += a * (v0.x + r.x);
        acc[1] += a * (v0.y + r.y);
        acc[2] += a * (v0.z + r.z);
        acc[3] += a * (v0.w + r.w);
    }
    #pragma unroll
    for (int j = 0; j < 4; ++j) {
        acc[j] += __shfl_xor(acc[j], 16, 64);
        acc[j] += __shfl_xor(acc[j], 32, 64);
    }
    if (mi == 0) {
        #pragma unroll
        for (int j = 0; j < 4; ++j) part[wave][4 * di + j] = acc[j];
    }
    __syncthreads();
    if (tid < DHEAD) {
        const float s = part[0][tid] + part[1][tid] + part[2][tid] + part[3][tid];
        ws_ctx[(size_t)l * DMODEL + h * DHEAD + tid] = s;
    }
}

// ---------------------------------------------------------------------------
// Kernel 4: output = context @ Wo + bo  (all fp32)
// ---------------------------------------------------------------------------
__global__ __launch_bounds__(256) void out_kernel(
    const float* __restrict__ ctx, const float* __restrict__ Wo,
    const float* __restrict__ bo, float* __restrict__ out)
{
    __shared__ float As[16][17];
    __shared__ float Bs[16][17];
    const int tx = threadIdx.x, ty = threadIdx.y;
    const int row = blockIdx.y * 16 + ty;
    const int col = blockIdx.x * 16 + tx;
    float acc = 0.f;
    for (int t = 0; t < DMODEL / 16; ++t) {
        As[ty][tx] = ctx[(size_t)row * DMODEL + t * 16 + tx];
        Bs[ty][tx] = Wo[(size_t)(t * 16 + ty) * DMODEL + col];
        __syncthreads();
        #pragma unroll
        for (int kk = 0; kk < 16; ++kk) acc += As[ty][kk] * Bs[kk][tx];
        __syncthreads();
    }
    out[(size_t)row * DMODEL + col] = acc + bo[col];
}

extern "C" void kernel_launch(void* const* d_in, const int* in_sizes, int n_in,
                              void* d_out, int out_size, void* d_ws, size_t ws_size,
                              hipStream_t stream)
{
    const float* query  = (const float*)d_in[0];
    const float* key_in = (const float*)d_in[1];
    const float* value  = (const float*)d_in[2];
    const float* rk     = (const float*)d_in[3];
    const float* rv     = (const float*)d_in[4];
    const float* Wq = (const float*)d_in[5];  const float* bq = (const float*)d_in[6];
    const float* Wk = (const float*)d_in[7];  const float* bk = (const float*)d_in[8];
    const float* Wv = (const float*)d_in[9];  const float* bv = (const float*)d_in[10];
    const float* Wo = (const float*)d_in[11]; const float* bo = (const float*)d_in[12];

    float* out      = (float*)d_out;                  // [512,512] output
    float* attn_out = out + (size_t)SEQ * DMODEL;     // [8,512,512] attn

    float* ws = (float*)d_ws;
    float* ws_q   = ws;                 // [512,512] fp32
    float* ws_k   = ws + 262144;        // [512,512] fp32
    float* ws_v   = ws + 524288;        // [512,512] fp32
    float* ws_ctx = ws + 786432;        // [512,512] fp32

    dim3 pb(16, 16);
    proj_kernel<<<dim3(32, 32, 3), pb, 0, stream>>>(query, key_in, value,
                                                    Wq, bq, Wk, bk, Wv, bv, ws);
    attn_kernel<<<dim3(512, 8), 256, 0, stream>>>(rk, ws_q, ws_k, attn_out);
    ctx_kernel<<<dim3(512, 8), 256, 0, stream>>>(rv, ws_v, attn_out, ws_ctx);
    out_kernel<<<dim3(32, 32), pb, 0, stream>>>(ws_ctx, Wo, bo, out);
}